// Round 5
// baseline (1517.847 us; speedup 1.0000x reference)
//
#include <hip/hip_runtime.h>
#include <float.h>

#define NB 16
#define N1 16384
#define NP1 512
#define NS1 32
#define N2 512
#define NP2 128
#define NS2 64
#define TILE1 2048

// ---------- numpy-exact float helpers (no FMA contraction) ----------
__device__ __forceinline__ float sq3_np(float x, float y, float z) {
#pragma clang fp contract(off)
  return ((x * x) + (y * y)) + (z * z);
}
__device__ __forceinline__ float dot3_np(float ax, float ay, float az,
                                         float bx, float by, float bz) {
#pragma clang fp contract(off)
  return ((ax * bx) + (ay * by)) + (az * bz);
}
__device__ __forceinline__ float sqr_np(float ca, float sb, float dot) {
#pragma clang fp contract(off)
  return (ca + sb) - (2.0f * dot);
}
__device__ __forceinline__ float distmin_np(float px, float py, float pz,
                                            float cx, float cy, float cz,
                                            float old) {
#pragma clang fp contract(off)
  float dx = px - cx, dy = py - cy, dz = pz - cz;
  float d = ((dx * dx) + (dy * dy)) + (dz * dz);
  return d < old ? d : old;
}

// ---------- workspace layout (float-unit offsets) ----------
constexpr size_t OFF_W1T1 = 0;        // 3x64   -> 192 (pad to 256)
constexpr size_t OFF_W2T1 = 256;      // 64x64  -> 4096
constexpr size_t OFF_W3T1 = 4352;     // 64x128 -> 8192
constexpr size_t OFF_W1T2 = 12544;    // 131x128-> 16768
constexpr size_t OFF_W2T2 = 29312;    // 128x256-> 32768
constexpr size_t OFF_W3T2 = 62080;    // 256x256-> 65536
constexpr size_t OFF_NORM1 = 127616;  // 16x16384
constexpr size_t OFF_L1XYZ = 389760;  // 16x512x3
constexpr size_t OFF_NORM2 = 414336;  // 16x512
constexpr size_t OFF_L1PTS = 422528;  // 16x512x128
constexpr size_t OFF_FPS1I = 1471104; // 16x512 ints
constexpr size_t OFF_FPS2I = 1479296; // 16x128 ints
constexpr size_t WS_FLOATS = 1481344;

// ---------- prep: point norms + weight transposes ----------
__global__ void prep_kernel(const float* __restrict__ xyz,
                            const float* __restrict__ w1a, const float* __restrict__ w2a,
                            const float* __restrict__ w3a, const float* __restrict__ w1b,
                            const float* __restrict__ w2b, const float* __restrict__ w3b,
                            float* __restrict__ ws) {
  int tid = blockIdx.x * blockDim.x + threadIdx.x;
  int stride = gridDim.x * blockDim.x;
  const int nNorm = NB * N1;
  const int e1 = nNorm + 192;
  const int e2 = e1 + 64 * 64;
  const int e3 = e2 + 128 * 64;
  const int e4 = e3 + 128 * 131;
  const int e5 = e4 + 256 * 128;
  const int e6 = e5 + 256 * 256;
  for (int i = tid; i < e6; i += stride) {
    if (i < nNorm) {
      ws[OFF_NORM1 + i] =
          sq3_np(xyz[(size_t)i * 3], xyz[(size_t)i * 3 + 1], xyz[(size_t)i * 3 + 2]);
    } else if (i < e1) {
      int j = i - nNorm; int o = j & 63, c = j >> 6;   // c<3
      ws[OFF_W1T1 + j] = w1a[o * 3 + c];
    } else if (i < e2) {
      int j = i - e1; int o = j & 63, c = j >> 6;
      ws[OFF_W2T1 + j] = w2a[o * 64 + c];
    } else if (i < e3) {
      int j = i - e2; int o = j & 127, c = j >> 7;
      ws[OFF_W3T1 + j] = w3a[o * 64 + c];
    } else if (i < e4) {
      int j = i - e3; int o = j & 127, c = j >> 7;     // c<131
      ws[OFF_W1T2 + j] = w1b[o * 131 + c];
    } else if (i < e5) {
      int j = i - e4; int o = j & 255, c = j >> 8;
      ws[OFF_W2T2 + j] = w2b[o * 128 + c];
    } else {
      int j = i - e5; int o = j & 255, c = j >> 8;
      ws[OFF_W3T2 + j] = w3b[o * 256 + c];
    }
  }
}

// ---------- FPS over N1=16384, npoint=512 ----------
// v5: SoA float4 LDS + ds_read_b128. Lessons r2-r4: LLVM remats read-only
// global loads (r2 VGPR=84), pins spill to scratch (r3), AoS scalar
// ds_read_b32 starves VGPR on address math (r4 VGPR=40, 83% VALU-busy on
// active CUs). So coords are re-read each step BY DESIGN via 3*CH
// ds_read_b128 from SoA [X|Y|Z] float4 regions (loop-invariant addresses);
// the only loop-carried state is dist[], which cannot be remat'd.
// Reduce: u64 key (dist_bits<<32 | ~idx, max = argmax + first-occurrence
// tie-break) + coords carried through the butterfly; lane 0 publishes.
template <int CH, int KR>
__global__ __launch_bounds__(512, 1) void fps1_kernel(const float* __restrict__ xyz,
                                                      int* __restrict__ out_idx) {
  constexpr int LDSP = CH * 2048;  // points resident in LDS
  extern __shared__ float4 spt4[]; // [3][CH*512] float4: X, Y, Z regions
  __shared__ unsigned long long s_key[2][8];
  __shared__ float s_cx[2][8], s_cy[2][8], s_cz[2][8];
  const int b = blockIdx.x;
  const int t = threadIdx.x;
  const int w = t >> 6;
  const int lane = t & 63;
  const float* xb = xyz + (size_t)b * N1 * 3;
  float* Xl = (float*)spt4;   // float-linear views; X[p] lands at region0
  float* Yl = Xl + LDSP;      // float4[p>>2] elem [p&3], so linear stores
  float* Zl = Yl + LDSP;      // produce exactly the chunked layout we read.
  for (int i = t; i < LDSP; i += 512) {
    Xl[i] = xb[3 * i];
    Yl[i] = xb[3 * i + 1];
    Zl[i] = xb[3 * i + 2];
  }
  float rx[KR], ry[KR], rz[KR];
#pragma unroll
  for (int k = 0; k < KR; ++k) {
    int p = LDSP + k * 512 + t;
    rx[k] = xb[p * 3]; ry[k] = xb[p * 3 + 1]; rz[k] = xb[p * 3 + 2];
  }
  float dl[4 * CH], dr[KR];
#pragma unroll
  for (int k = 0; k < 4 * CH; ++k) dl[k] = 1e10f;
#pragma unroll
  for (int k = 0; k < KR; ++k) dr[k] = 1e10f;
  if (t == 0) out_idx[b * NP1] = 0;
  float cx = xb[0], cy = xb[1], cz = xb[2];
  __syncthreads();  // LDS staged
  for (int s = 1; s < NP1; ++s) {
    const int par = s & 1;
    float bv = -1.0f;
    unsigned int gi = 0;
    float wx = 0.f, wy = 0.f, wz = 0.f;
#pragma unroll
    for (int c = 0; c < CH; ++c) {
      float4 x4 = spt4[c * 512 + t];
      float4 y4 = spt4[CH * 512 + c * 512 + t];
      float4 z4 = spt4[2 * CH * 512 + c * 512 + t];
      unsigned int p0 = (unsigned)(c * 2048 + 4 * t);
      float nd0 = distmin_np(x4.x, y4.x, z4.x, cx, cy, cz, dl[4 * c + 0]);
      dl[4 * c + 0] = nd0;
      if (nd0 > bv) { bv = nd0; gi = p0; wx = x4.x; wy = y4.x; wz = z4.x; }
      float nd1 = distmin_np(x4.y, y4.y, z4.y, cx, cy, cz, dl[4 * c + 1]);
      dl[4 * c + 1] = nd1;
      if (nd1 > bv) { bv = nd1; gi = p0 + 1; wx = x4.y; wy = y4.y; wz = z4.y; }
      float nd2 = distmin_np(x4.z, y4.z, z4.z, cx, cy, cz, dl[4 * c + 2]);
      dl[4 * c + 2] = nd2;
      if (nd2 > bv) { bv = nd2; gi = p0 + 2; wx = x4.z; wy = y4.z; wz = z4.z; }
      float nd3 = distmin_np(x4.w, y4.w, z4.w, cx, cy, cz, dl[4 * c + 3]);
      dl[4 * c + 3] = nd3;
      if (nd3 > bv) { bv = nd3; gi = p0 + 3; wx = x4.w; wy = y4.w; wz = z4.w; }
    }
#pragma unroll
    for (int k = 0; k < KR; ++k) {
      float nd = distmin_np(rx[k], ry[k], rz[k], cx, cy, cz, dr[k]);
      dr[k] = nd;
      if (nd > bv) { bv = nd; gi = (unsigned)(LDSP + k * 512) + (unsigned)t;
                     wx = rx[k]; wy = ry[k]; wz = rz[k]; }
    }
    unsigned long long key =
        ((unsigned long long)__float_as_uint(bv) << 32) | (unsigned int)~gi;
#pragma unroll
    for (int off = 1; off < 64; off <<= 1) {
      unsigned long long ok = __shfl_xor(key, off);
      float ox = __shfl_xor(wx, off), oy = __shfl_xor(wy, off), oz = __shfl_xor(wz, off);
      if (ok > key) { key = ok; wx = ox; wy = oy; wz = oz; }
    }
    if (lane == 0) {
      s_key[par][w] = key;
      s_cx[par][w] = wx; s_cy[par][w] = wy; s_cz[par][w] = wz;
    }
    __syncthreads();  // single barrier/step; parity buffer kills WAR hazard
    unsigned long long fk = s_key[par][0];
    int fw = 0;
#pragma unroll
    for (int i = 1; i < 8; ++i) {
      unsigned long long k2 = s_key[par][i];
      bool gt = k2 > fk;
      fk = gt ? k2 : fk;
      fw = gt ? i : fw;
    }
    cx = s_cx[par][fw]; cy = s_cy[par][fw]; cz = s_cz[par][fw];  // LDS broadcast
    if (t == 0) out_idx[b * NP1 + s] = (int)(~(unsigned int)fk);
  }
}

// ---------- FPS over N2=512, npoint=128 : 16 blocks x 64 threads (1 wave) ----------
__global__ __launch_bounds__(64) void fps2_kernel(const float* __restrict__ l1_xyz,
                                                  int* __restrict__ out_idx) {
  __shared__ float spt[N2 * 3];
  int b = blockIdx.x;
  int lane = threadIdx.x;
  const float* xb = l1_xyz + (size_t)b * N2 * 3;
  for (int i = lane; i < N2 * 3; i += 64) spt[i] = xb[i];
  float dist[8];
#pragma unroll
  for (int k = 0; k < 8; ++k) dist[k] = 1e10f;
  if (lane == 0) out_idx[b * NP2] = 0;
  float cx = xb[0], cy = xb[1], cz = xb[2];
  __syncthreads();
  for (int s = 1; s < NP2; ++s) {
    float bv = -1.0f;
    unsigned int gi = 0;
#pragma unroll
    for (int k = 0; k < 8; ++k) {
      int p = k * 64 + lane;
      float x = spt[3 * p], y = spt[3 * p + 1], z = spt[3 * p + 2];
      float nd = distmin_np(x, y, z, cx, cy, cz, dist[k]);
      dist[k] = nd;
      if (nd > bv) { bv = nd; gi = (unsigned)p; }
    }
    unsigned long long key =
        ((unsigned long long)__float_as_uint(bv) << 32) | (unsigned int)~gi;
#pragma unroll
    for (int off = 1; off < 64; off <<= 1) {
      unsigned long long ok = __shfl_xor(key, off);
      if (ok > key) key = ok;
    }
    unsigned int fi = ~(unsigned int)key;  // all lanes agree after butterfly
    cx = spt[3 * fi]; cy = spt[3 * fi + 1]; cz = spt[3 * fi + 2];
    if (lane == 0) out_idx[b * NP2 + s] = (int)fi;
  }
}

// ---------- SA1 fused: ball query (first-32 ascending) + MLP(3->64->64->128) + max ----------
__global__ __launch_bounds__(256) void sa1_kernel(
    const float* __restrict__ xyz, const float* __restrict__ norms1,
    const int* __restrict__ fps1_idx,
    const float* __restrict__ w1T, const float* __restrict__ bias1,
    const float* __restrict__ w2T, const float* __restrict__ bias2,
    const float* __restrict__ w3T, const float* __restrict__ bias3,
    float* __restrict__ l1_xyz, float* __restrict__ norms2, float* __restrict__ l1_pts) {
  __shared__ float4 tile[TILE1];
  __shared__ float blx[4 * NS1], bly[4 * NS1], blz[4 * NS1];
  int b = blockIdx.x >> 7;
  int t = threadIdx.x;
  int w = t >> 6, lane = t & 63;
  int s = ((blockIdx.x & 127) << 2) + w;
  const float* xb = xyz + (size_t)b * N1 * 3;
  const float* nb = norms1 + (size_t)b * N1;
  int cidx = fps1_idx[b * NP1 + s];
  float cx = xb[cidx * 3], cy = xb[cidx * 3 + 1], cz = xb[cidx * 3 + 2];
  float ca = nb[cidx];
  const float r2 = (float)(0.04 * 0.04);
  int tot = 0;
  for (int t0 = 0; t0 < N1; t0 += TILE1) {
    for (int i = t; i < TILE1; i += 256) {
      int p = t0 + i;
      tile[i] = make_float4(xb[p * 3], xb[p * 3 + 1], xb[p * 3 + 2], nb[p]);
    }
    __syncthreads();
    for (int j = 0; j < TILE1; j += 256) {
      float4 p0 = tile[j + lane];
      float4 p1 = tile[j + 64 + lane];
      float4 p2 = tile[j + 128 + lane];
      float4 p3 = tile[j + 192 + lane];
      bool in0 = !(sqr_np(ca, p0.w, dot3_np(cx, cy, cz, p0.x, p0.y, p0.z)) > r2);
      bool in1 = !(sqr_np(ca, p1.w, dot3_np(cx, cy, cz, p1.x, p1.y, p1.z)) > r2);
      bool in2 = !(sqr_np(ca, p2.w, dot3_np(cx, cy, cz, p2.x, p2.y, p2.z)) > r2);
      bool in3 = !(sqr_np(ca, p3.w, dot3_np(cx, cy, cz, p3.x, p3.y, p3.z)) > r2);
      unsigned long long any = __ballot(in0 | in1 | in2 | in3);
      if (any) {
#define SA1_APPEND(inq, pq)                                                     \
        {                                                                       \
          unsigned long long m = __ballot(inq);                                 \
          if (m) {                                                              \
            int rank = __popcll(m & ((1ull << lane) - 1ull));                   \
            int slot = tot + rank;                                              \
            if (inq && slot < NS1) {                                            \
              blx[w * NS1 + slot] = pq.x - cx;                                  \
              bly[w * NS1 + slot] = pq.y - cy;                                  \
              blz[w * NS1 + slot] = pq.z - cz;                                  \
            }                                                                   \
            tot += (int)__popcll(m);                                            \
            if (tot > NS1) tot = NS1;                                           \
          }                                                                     \
        }
        SA1_APPEND(in0, p0)
        SA1_APPEND(in1, p1)
        SA1_APPEND(in2, p2)
        SA1_APPEND(in3, p3)
#undef SA1_APPEND
      }
    }
    __syncthreads();
  }
  int cnt = tot > 0 ? tot : 1;  // centroid is always in its own ball
  float m0 = -FLT_MAX, m1 = -FLT_MAX;
  for (int k = 0; k < cnt; ++k) {
    float fx = blx[w * NS1 + k], fy = bly[w * NS1 + k], fz = blz[w * NS1 + k];
    float h1 = bias1[lane] + w1T[lane] * fx + w1T[64 + lane] * fy + w1T[128 + lane] * fz;
    h1 = fmaxf(h1, 0.0f);
    float a = bias2[lane];
#pragma unroll 8
    for (int c = 0; c < 64; ++c) a += w2T[c * 64 + lane] * __shfl(h1, c);
    a = fmaxf(a, 0.0f);
    float a0 = bias3[lane], a1 = bias3[64 + lane];
#pragma unroll 8
    for (int c = 0; c < 64; ++c) {
      float hv = __shfl(a, c);
      a0 += w3T[c * 128 + lane] * hv;
      a1 += w3T[c * 128 + 64 + lane] * hv;
    }
    a0 = fmaxf(a0, 0.0f); a1 = fmaxf(a1, 0.0f);
    m0 = fmaxf(m0, a0); m1 = fmaxf(m1, a1);
  }
  float* op = l1_pts + ((size_t)b * NP1 + s) * 128;
  op[lane] = m0;
  op[64 + lane] = m1;
  if (lane == 0) {
    float* xp = l1_xyz + ((size_t)b * NP1 + s) * 3;
    xp[0] = cx; xp[1] = cy; xp[2] = cz;
    norms2[b * NP1 + s] = ca;
  }
}

// ---------- SA2 fused: ball query (first-64) + MLP(131->128->256->256) + max ----------
__global__ __launch_bounds__(256) void sa2_kernel(
    const float* __restrict__ l1_xyz, const float* __restrict__ norms2,
    const float* __restrict__ l1_pts, const int* __restrict__ fps2_idx,
    const float* __restrict__ w1T, const float* __restrict__ bias1,
    const float* __restrict__ w2T, const float* __restrict__ bias2,
    const float* __restrict__ w3T, const float* __restrict__ bias3,
    float* __restrict__ out) {
  __shared__ float sx[N2], sy[N2], sz[N2], sn[N2];
  __shared__ float blx[4 * NS2], bly[4 * NS2], blz[4 * NS2];
  __shared__ int bli[4 * NS2];
  int b = blockIdx.x >> 5;
  int t = threadIdx.x;
  int w = t >> 6, lane = t & 63;
  int s = ((blockIdx.x & 31) << 2) + w;
  const float* xb = l1_xyz + (size_t)b * N2 * 3;
  const float* nb = norms2 + (size_t)b * N2;
  for (int i = t; i < N2; i += 256) {
    sx[i] = xb[i * 3]; sy[i] = xb[i * 3 + 1]; sz[i] = xb[i * 3 + 2]; sn[i] = nb[i];
  }
  __syncthreads();
  int cidx = fps2_idx[b * NP2 + s];
  float cx = sx[cidx], cy = sy[cidx], cz = sz[cidx], ca = sn[cidx];
  const float r2 = (float)(0.08 * 0.08);
  int tot = 0;
  for (int j = 0; j < N2; j += 64) {
    int i = j + lane;
    float px = sx[i], py = sy[i], pz = sz[i], sb = sn[i];
    bool in = !(sqr_np(ca, sb, dot3_np(cx, cy, cz, px, py, pz)) > r2);
    unsigned long long m = __ballot(in);
    int rank = __popcll(m & ((1ull << lane) - 1ull));
    int slot = tot + rank;
    if (in && slot < NS2) {
      blx[w * NS2 + slot] = px - cx;
      bly[w * NS2 + slot] = py - cy;
      blz[w * NS2 + slot] = pz - cz;
      bli[w * NS2 + slot] = i;
    }
    tot += (int)__popcll(m);
    if (tot > NS2) tot = NS2;
  }
  __syncthreads();
  int cnt = tot > 0 ? tot : 1;
  float mx0 = -FLT_MAX, mx1 = -FLT_MAX, mx2 = -FLT_MAX, mx3 = -FLT_MAX;
  for (int k = 0; k < cnt; ++k) {
    float fx = blx[w * NS2 + k], fy = bly[w * NS2 + k], fz = blz[w * NS2 + k];
    int pidx = bli[w * NS2 + k];
    const float* fp = l1_pts + ((size_t)b * N2 + pidx) * 128;
    float a0 = bias1[lane] + w1T[lane] * fx + w1T[128 + lane] * fy + w1T[256 + lane] * fz;
    float a1 = bias1[64 + lane] + w1T[64 + lane] * fx + w1T[192 + lane] * fy + w1T[320 + lane] * fz;
#pragma unroll 4
    for (int c = 0; c < 128; ++c) {
      float fv = fp[c];
      a0 += w1T[(size_t)(3 + c) * 128 + lane] * fv;
      a1 += w1T[(size_t)(3 + c) * 128 + 64 + lane] * fv;
    }
    float h1a = fmaxf(a0, 0.0f), h1b = fmaxf(a1, 0.0f);
    float acc0 = bias2[lane], acc1 = bias2[64 + lane], acc2 = bias2[128 + lane], acc3 = bias2[192 + lane];
#pragma unroll 4
    for (int c = 0; c < 64; ++c) {
      float hv = __shfl(h1a, c);
      acc0 += w2T[(size_t)c * 256 + lane] * hv;
      acc1 += w2T[(size_t)c * 256 + 64 + lane] * hv;
      acc2 += w2T[(size_t)c * 256 + 128 + lane] * hv;
      acc3 += w2T[(size_t)c * 256 + 192 + lane] * hv;
    }
#pragma unroll 4
    for (int c = 0; c < 64; ++c) {
      float hv = __shfl(h1b, c);
      acc0 += w2T[(size_t)(64 + c) * 256 + lane] * hv;
      acc1 += w2T[(size_t)(64 + c) * 256 + 64 + lane] * hv;
      acc2 += w2T[(size_t)(64 + c) * 256 + 128 + lane] * hv;
      acc3 += w2T[(size_t)(64 + c) * 256 + 192 + lane] * hv;
    }
    float h20 = fmaxf(acc0, 0.0f), h21 = fmaxf(acc1, 0.0f);
    float h22 = fmaxf(acc2, 0.0f), h23 = fmaxf(acc3, 0.0f);
    float o0 = bias3[lane], o1 = bias3[64 + lane], o2 = bias3[128 + lane], o3 = bias3[192 + lane];
#define SA2_L3(hreg, rbase)                                                     \
    {                                                                           \
      _Pragma("unroll 4")                                                       \
      for (int c = 0; c < 64; ++c) {                                            \
        float hv = __shfl(hreg, c);                                             \
        o0 += w3T[(size_t)(rbase + c) * 256 + lane] * hv;                       \
        o1 += w3T[(size_t)(rbase + c) * 256 + 64 + lane] * hv;                  \
        o2 += w3T[(size_t)(rbase + c) * 256 + 128 + lane] * hv;                 \
        o3 += w3T[(size_t)(rbase + c) * 256 + 192 + lane] * hv;                 \
      }                                                                         \
    }
    SA2_L3(h20, 0)
    SA2_L3(h21, 64)
    SA2_L3(h22, 128)
    SA2_L3(h23, 192)
#undef SA2_L3
    mx0 = fmaxf(mx0, fmaxf(o0, 0.0f));
    mx1 = fmaxf(mx1, fmaxf(o1, 0.0f));
    mx2 = fmaxf(mx2, fmaxf(o2, 0.0f));
    mx3 = fmaxf(mx3, fmaxf(o3, 0.0f));
  }
  float* op = out + ((size_t)b * NP2 + s) * 256;
  op[lane] = mx0;
  op[64 + lane] = mx1;
  op[128 + lane] = mx2;
  op[192 + lane] = mx3;
}

extern "C" void kernel_launch(void* const* d_in, const int* in_sizes, int n_in,
                              void* d_out, int out_size, void* d_ws, size_t ws_size,
                              hipStream_t stream) {
  const float* xyz = (const float*)d_in[0];
  const float* sa1_w1 = (const float*)d_in[1];
  const float* sa1_b1 = (const float*)d_in[2];
  const float* sa1_w2 = (const float*)d_in[3];
  const float* sa1_b2 = (const float*)d_in[4];
  const float* sa1_w3 = (const float*)d_in[5];
  const float* sa1_b3 = (const float*)d_in[6];
  const float* sa2_w1 = (const float*)d_in[7];
  const float* sa2_b1 = (const float*)d_in[8];
  const float* sa2_w2 = (const float*)d_in[9];
  const float* sa2_b2 = (const float*)d_in[10];
  const float* sa2_w3 = (const float*)d_in[11];
  const float* sa2_b3 = (const float*)d_in[12];

  if (ws_size < WS_FLOATS * sizeof(float)) return;  // scratch too small: fail loudly

  float* ws = (float*)d_ws;
  float* w1T1 = ws + OFF_W1T1;
  float* w2T1 = ws + OFF_W2T1;
  float* w3T1 = ws + OFF_W3T1;
  float* w1T2 = ws + OFF_W1T2;
  float* w2T2 = ws + OFF_W2T2;
  float* w3T2 = ws + OFF_W3T2;
  float* norms1 = ws + OFF_NORM1;
  float* l1xyz = ws + OFF_L1XYZ;
  float* norms2 = ws + OFF_NORM2;
  float* l1pts = ws + OFF_L1PTS;
  int* fps1i = (int*)(ws + OFF_FPS1I);
  int* fps2i = (int*)(ws + OFF_FPS2I);

  prep_kernel<<<1024, 256, 0, stream>>>(xyz, sa1_w1, sa1_w2, sa1_w3, sa2_w1, sa2_w2, sa2_w3, ws);

  // SoA LDS variant: 12288 pts -> 144KB dynamic (opt-in attribute, capture-
  // safe). Fallback: 4096 pts -> 48KB dynamic, 24 residual pts/thread.
  constexpr size_t DYN_BIG = (size_t)12288 * 3 * sizeof(float);   // CH=6
  hipError_t attr_ok = hipFuncSetAttribute(
      reinterpret_cast<const void*>(&fps1_kernel<6, 8>),
      hipFuncAttributeMaxDynamicSharedMemorySize, (int)DYN_BIG);
  if (attr_ok == hipSuccess) {
    fps1_kernel<6, 8><<<NB, 512, DYN_BIG, stream>>>(xyz, fps1i);
  } else {
    fps1_kernel<2, 24>
        <<<NB, 512, (size_t)4096 * 3 * sizeof(float), stream>>>(xyz, fps1i);
  }

  sa1_kernel<<<NB * (NP1 / 4), 256, 0, stream>>>(xyz, norms1, fps1i, w1T1, sa1_b1, w2T1,
                                                 sa1_b2, w3T1, sa1_b3, l1xyz, norms2, l1pts);
  fps2_kernel<<<NB, 64, 0, stream>>>(l1xyz, fps2i);
  sa2_kernel<<<NB * (NP2 / 4), 256, 0, stream>>>(l1xyz, norms2, l1pts, fps2i, w1T2, sa2_b1,
                                                 w2T2, sa2_b2, w3T2, sa2_b3, (float*)d_out);
}